// Round 7
// baseline (270.895 us; speedup 1.0000x reference)
//
#include <hip/hip_runtime.h>

#define PH_ 7
#define PW_ 7
#define C_ 256
#define H_ 200
#define W_ 272
#define HW_ (H_*W_)
#define NBIN 49
#define MAXE (4*C_*HW_)       // total feature elements
#define WAVE_LDS 8192         // ring-buffer bytes per wave

typedef __attribute__((address_space(1))) const void glb_v;
typedef __attribute__((address_space(3))) void lds_v;
typedef float f2_t __attribute__((ext_vector_type(2), aligned(4)));

template<int K>
__device__ __forceinline__ void issueK(const float* fp, const int* goff,
                                       char* dst, const float* fend) {
#pragma unroll
  for (int i = 0; i < K; ++i) {
    const float* src = fp + goff[i];
    if (src > fend) src = fend;       // tail clamp (never-read slots only)
    __builtin_amdgcn_global_load_lds((glb_v*)src, (lds_v*)(dst + i * 1024),
                                     16, 0, 0);
  }
}

// Ring pipeline, depth D (power of 2, D>=1). Iter j: issue ch j+D-1 into slot
// (j+D-1)&(D-1), counted wait (loads retire in-order -> ch j's batch landed),
// compute slot j&(D-1). D==1 degenerates to serial issue+vmcnt(0). No barriers.
#define BODY(KC, D, NW)                                                        \
  {                                                                            \
    const int BSZ = (KC) * 1024;                                               \
    _Pragma("unroll")                                                          \
    for (int d = 0; d < (D) - 1; ++d)                                          \
      issueK<(KC)>(fptr + (size_t)(4 * HW_) * d, goff, b0 + d * BSZ, fend);    \
    for (int j = 0; j < 64; ++j) {                                             \
      const float* fsrc =                                                      \
          (j + (D) - 1 < 64) ? fptr + (size_t)(4 * HW_) * ((D) - 1) : fptr;    \
      issueK<(KC)>(fsrc, goff, b0 + (((j + (D) - 1) & ((D) - 1)) * BSZ), fend);\
      asm volatile("s_waitcnt vmcnt(" #NW ")" ::: "memory");                   \
      if (act) {                                                               \
        const float* t = (const float*)(b0 + ((j & ((D) - 1)) * BSZ));         \
        float a0 = 0.f, a1 = 0.f, a2 = 0.f, a3 = 0.f;                          \
        f2_t p0 = *(const f2_t*)(t + a8[0]);                                   \
        f2_t p1 = *(const f2_t*)(t + a8[1]);                                   \
        f2_t p2 = *(const f2_t*)(t + a8[2]);                                   \
        f2_t p3 = *(const f2_t*)(t + a8[3]);                                   \
        a0 = fmaf(wl8[0], p0.x, fmaf(wr8[0], p0.y, a0));                       \
        a1 = fmaf(wl8[1], p1.x, fmaf(wr8[1], p1.y, a1));                       \
        a2 = fmaf(wl8[2], p2.x, fmaf(wr8[2], p2.y, a2));                       \
        a3 = fmaf(wl8[3], p3.x, fmaf(wr8[3], p3.y, a3));                       \
        p0 = *(const f2_t*)(t + a8[4]);                                        \
        p1 = *(const f2_t*)(t + a8[5]);                                        \
        p2 = *(const f2_t*)(t + a8[6]);                                        \
        p3 = *(const f2_t*)(t + a8[7]);                                        \
        a0 = fmaf(wl8[4], p0.x, fmaf(wr8[4], p0.y, a0));                       \
        a1 = fmaf(wl8[5], p1.x, fmaf(wr8[5], p1.y, a1));                       \
        a2 = fmaf(wl8[6], p2.x, fmaf(wr8[6], p2.y, a2));                       \
        a3 = fmaf(wl8[7], p3.x, fmaf(wr8[7], p3.y, a3));                       \
        *optr = (a0 + a1) + (a2 + a3);                                         \
      }                                                                        \
      fptr += 4 * HW_;                                                         \
      optr += 4 * NBIN;                                                        \
    }                                                                          \
  }

__global__ __launch_bounds__(128, 5)
void roialign_kernel(const float* __restrict__ feat,
                     const float* __restrict__ rois,
                     float* __restrict__ out) {
  __shared__ __align__(16) char smem[2 * WAVE_LDS];   // 16 KB: one ring per wave

  const int bid = blockIdx.x;
  const int n = bid >> 1;
  const int h = bid & 1;
  const int tid = threadIdx.x;
  const int lane = tid & 63;
  const int wid = tid >> 6;
  const float* roi = rois + (size_t)n * 5;

  // ---- fully per-thread redundant ROI precompute (no LDS, no barriers) ----
  float rx1 = roi[1] * 0.0625f, ry1 = roi[2] * 0.0625f;
  float rx2 = roi[3] * 0.0625f, ry2 = roi[4] * 0.0625f;
  const int base = (int)roi[0] * (C_ * HW_);
  float bin_w = fmaxf(rx2 - rx1, 1.0f) * (1.0f / 7.0f);
  float bin_h = fmaxf(ry2 - ry1, 1.0f) * (1.0f / 7.0f);

  const bool act = lane < NBIN;
  const int bin = act ? lane : 0;
  const int myph = bin / PW_;
  const int mypw = bin - myph * PW_;

  int ymin = H_, ymax = 0, cmin = W_, cmax = 0;
  int rowv[4]; float wy[4];
#pragma unroll
  for (int p = 0; p < PH_; ++p) {
#pragma unroll
    for (int iy = 0; iy < 2; ++iy) {
      float y = ry1 + (float)p * bin_h + ((float)iy + 0.5f) * bin_h * 0.5f;
      float v = (y >= -1.0f && y <= (float)H_) ? 1.0f : 0.0f;
      float yc = fminf(fmaxf(y, 0.0f), (float)(H_ - 1));
      int y0 = (int)floorf(yc);
      if (y0 > H_ - 1) y0 = H_ - 1;
      int y1i = min(y0 + 1, H_ - 1);
      float ly = yc - (float)y0;
      float hy = 1.0f - ly;
      ymin = min(ymin, y0); ymax = max(ymax, y1i);
      if (p == myph) {
        rowv[2 * iy] = y0;  rowv[2 * iy + 1] = y1i;
        wy[2 * iy] = hy * v; wy[2 * iy + 1] = ly * v;
      }
    }
  }
  int cc2[2]; float wxl[2], wxr[2];
#pragma unroll
  for (int p = 0; p < PW_; ++p) {
#pragma unroll
    for (int ix = 0; ix < 2; ++ix) {
      float x = rx1 + (float)p * bin_w + ((float)ix + 0.5f) * bin_w * 0.5f;
      float v = (x >= -1.0f && x <= (float)W_) ? 0.25f : 0.0f;
      float xc = fminf(fmaxf(x, 0.0f), (float)(W_ - 1));
      int x0 = (int)floorf(xc);
      float lx = xc - (float)x0;
      float hx = 1.0f - lx;
      int c; float wl, wr;
      if (x0 >= W_ - 1) { c = W_ - 2; wl = 0.0f; wr = hx * v; }
      else              { c = x0;     wl = hx * v; wr = lx * v; }
      cmin = min(cmin, c); cmax = max(cmax, c);
      if (p == mypw) { cc2[ix] = c; wxl[ix] = wl; wxr[ix] = wr; }
    }
  }

  const int xs4 = cmin & ~3;
  const int ng4 = ((cmax + 5 - xs4) >> 2) | 1;  // odd -> stride hits all banks
  const int nf4 = (ymax - ymin + 1) * ng4;      // <= 288
  const int S4  = 4 * ng4;                      // row stride in floats

  // ---- staging descriptors (linear packed layout) ----
  int goff[5];
#pragma unroll
  for (int i = 0; i < 5; ++i) {
    int idx = lane + 64 * i;
    int ii = min(idx, nf4 - 1);
    int row = ii / ng4;
    int g = ii - row * ng4;
    goff[i] = (ymin + row) * W_ + xs4 + 4 * g;
  }

  // ---- compute descriptors: 8 adjacent-pair taps ----
  int a8[8]; float wl8[8], wr8[8];
#pragma unroll
  for (int r = 0; r < 4; ++r)
#pragma unroll
    for (int s = 0; s < 2; ++s) {
      int q = r * 2 + s;
      a8[q] = (rowv[r] - ymin) * S4 + (cc2[s] - xs4);
      wl8[q] = wy[r] * wxl[s];
      wr8[q] = wy[r] * wxr[s];
    }

  const int cstart = 2 * h + wid;            // channel residue mod 4
  const float* fptr = feat + (size_t)base + (size_t)cstart * HW_;
  float* optr = out + (size_t)n * (C_ * NBIN) + cstart * NBIN + lane;
  const float* fend = feat + (MAXE - 4);
  char* b0 = smem + wid * WAVE_LDS;

  const int K = (nf4 + 63) >> 6;             // 1..5, wave-uniform
  switch (K) {
    case 1: BODY(1, 8, 7); break;            // ring 8 deep, wait (8-1)*1
    case 2: BODY(2, 4, 6); break;            // wait (4-1)*2
    case 3: BODY(3, 2, 3); break;            // wait (2-1)*3
    case 4: BODY(4, 2, 4); break;            // wait (2-1)*4
    default: BODY(5, 1, 0); break;           // serial
  }
}

extern "C" void kernel_launch(void* const* d_in, const int* in_sizes, int n_in,
                              void* d_out, int out_size, void* d_ws, size_t ws_size,
                              hipStream_t stream) {
  const float* feat = (const float*)d_in[0];
  const float* rois = (const float*)d_in[1];
  float* out = (float*)d_out;
  int N = in_sizes[1] / 5;  // rois is (N,5)
  roialign_kernel<<<dim3(N * 2), dim3(128), 0, stream>>>(feat, rois, out);
}

// Round 8
// 197.206 us; speedup vs baseline: 1.3737x; 1.3737x over previous
//
#include <hip/hip_runtime.h>

#define PH_ 7
#define PW_ 7
#define C_ 256
#define H_ 200
#define W_ 272
#define HW_ (H_*W_)
#define NBIN 49
#define MAXE (4*C_*HW_)       // total feature elements
#define CPB 16                // channels per block (grid slow dim = 256/CPB chunks)
#define CPW 8                 // channels per wave (2 waves/block)
#define WAVE_LDS 10240        // ring bytes per wave (max: K=5 x 2 slots)

typedef __attribute__((address_space(1))) const void glb_v;
typedef __attribute__((address_space(3))) void lds_v;
typedef float f2_t __attribute__((ext_vector_type(2), aligned(4)));

template<int K>
__device__ __forceinline__ void issueK(const float* fp, const int* goff,
                                       char* dst, const float* fend) {
#pragma unroll
  for (int i = 0; i < K; ++i) {
    const float* src = fp + goff[i];
    if (src > fend) src = fend;       // tail clamp (never-read slots only)
    __builtin_amdgcn_global_load_lds((glb_v*)src, (lds_v*)(dst + i * 1024),
                                     16, 0, 0);
  }
}

#define COMPUTE(SLOT)                                                        \
  if (act) {                                                                 \
    const float* t = (const float*)(SLOT);                                   \
    float a0 = 0.f, a1 = 0.f, a2 = 0.f, a3 = 0.f;                            \
    f2_t p0 = *(const f2_t*)(t + a8[0]);                                     \
    f2_t p1 = *(const f2_t*)(t + a8[1]);                                     \
    f2_t p2 = *(const f2_t*)(t + a8[2]);                                     \
    f2_t p3 = *(const f2_t*)(t + a8[3]);                                     \
    a0 = fmaf(wl8[0], p0.x, fmaf(wr8[0], p0.y, a0));                         \
    a1 = fmaf(wl8[1], p1.x, fmaf(wr8[1], p1.y, a1));                         \
    a2 = fmaf(wl8[2], p2.x, fmaf(wr8[2], p2.y, a2));                         \
    a3 = fmaf(wl8[3], p3.x, fmaf(wr8[3], p3.y, a3));                         \
    p0 = *(const f2_t*)(t + a8[4]);                                          \
    p1 = *(const f2_t*)(t + a8[5]);                                          \
    p2 = *(const f2_t*)(t + a8[6]);                                          \
    p3 = *(const f2_t*)(t + a8[7]);                                          \
    a0 = fmaf(wl8[4], p0.x, fmaf(wr8[4], p0.y, a0));                         \
    a1 = fmaf(wl8[5], p1.x, fmaf(wr8[5], p1.y, a1));                         \
    a2 = fmaf(wl8[6], p2.x, fmaf(wr8[6], p2.y, a2));                         \
    a3 = fmaf(wl8[7], p3.x, fmaf(wr8[7], p3.y, a3));                         \
    *optr = (a0 + a1) + (a2 + a3);                                           \
  }                                                                          \
  fptr += HW_;                                                               \
  optr += NBIN;

// Depth-2 ring over CPW consecutive channels; exact counted waits, no dummy
// reissues. Iter j: issue ch j+1 into other slot, wait KC (batch j landed),
// compute slot j&1. Tail waits 0.
#define BODY2(KC)                                                            \
  {                                                                          \
    char* s0 = b0;                                                           \
    char* s1 = b0 + (KC) * 1024;                                             \
    issueK<KC>(fptr, goff, s0, fend);                                        \
    _Pragma("unroll")                                                        \
    for (int j = 0; j < CPW - 1; ++j) {                                      \
      issueK<KC>(fptr + HW_, goff, (j & 1) ? s0 : s1, fend);                 \
      asm volatile("s_waitcnt vmcnt(" #KC ")" ::: "memory");                 \
      COMPUTE((j & 1) ? s1 : s0);                                            \
    }                                                                        \
    asm volatile("s_waitcnt vmcnt(0)" ::: "memory");                         \
    COMPUTE(((CPW - 1) & 1) ? s1 : s0);                                      \
  }

// Depth-3 ring (2 channels in flight) for small K; exact epilogue waits.
#define BODY3(KC, NW2, NW1)                                                  \
  {                                                                          \
    char* sl[3] = {b0, b0 + (KC) * 1024, b0 + 2 * (KC) * 1024};              \
    issueK<KC>(fptr, goff, sl[0], fend);                                     \
    issueK<KC>(fptr + HW_, goff, sl[1], fend);                               \
    _Pragma("unroll")                                                        \
    for (int j = 0; j < CPW; ++j) {                                          \
      char* cur = (j % 3 == 0) ? sl[0] : ((j % 3 == 1) ? sl[1] : sl[2]);     \
      if (j < CPW - 2) {                                                     \
        char* dst =                                                          \
            ((j + 2) % 3 == 0) ? sl[0] : (((j + 2) % 3 == 1) ? sl[1] : sl[2]);\
        issueK<KC>(fptr + 2 * HW_, goff, dst, fend);                         \
        asm volatile("s_waitcnt vmcnt(" #NW2 ")" ::: "memory");              \
      } else if (j == CPW - 2) {                                             \
        asm volatile("s_waitcnt vmcnt(" #NW1 ")" ::: "memory");              \
      } else {                                                               \
        asm volatile("s_waitcnt vmcnt(0)" ::: "memory");                     \
      }                                                                      \
      COMPUTE(cur);                                                          \
    }                                                                        \
  }

__global__ __launch_bounds__(128, 4)
void roialign_kernel(const float* __restrict__ feat,
                     const float* __restrict__ rois,
                     float* __restrict__ out, int Nrois) {
  __shared__ __align__(16) char smem[2 * WAVE_LDS];   // 20 KB: one ring per wave

  const int bid = blockIdx.x;
  const int n = bid % Nrois;          // fast dim: ROI
  const int chunk = bid / Nrois;      // slow dim: channel chunk (phase-aligned)
  const int tid = threadIdx.x;
  const int lane = tid & 63;
  const int wid = tid >> 6;
  const float* roi = rois + (size_t)n * 5;

  // ---- per-thread redundant ROI precompute (no LDS params, no barriers) ----
  float rx1 = roi[1] * 0.0625f, ry1 = roi[2] * 0.0625f;
  float rx2 = roi[3] * 0.0625f, ry2 = roi[4] * 0.0625f;
  const int base = (int)roi[0] * (C_ * HW_);
  float bin_w = fmaxf(rx2 - rx1, 1.0f) * (1.0f / 7.0f);
  float bin_h = fmaxf(ry2 - ry1, 1.0f) * (1.0f / 7.0f);

  const bool act = lane < NBIN;
  const int bin = act ? lane : 0;
  const int myph = bin / PW_;
  const int mypw = bin - myph * PW_;

  int ymin = H_, ymax = 0, cmin = W_, cmax = 0;
  int rowv[4]; float wy[4];
#pragma unroll
  for (int p = 0; p < PH_; ++p) {
#pragma unroll
    for (int iy = 0; iy < 2; ++iy) {
      float y = ry1 + (float)p * bin_h + ((float)iy + 0.5f) * bin_h * 0.5f;
      float v = (y >= -1.0f && y <= (float)H_) ? 1.0f : 0.0f;
      float yc = fminf(fmaxf(y, 0.0f), (float)(H_ - 1));
      int y0 = (int)floorf(yc);
      if (y0 > H_ - 1) y0 = H_ - 1;
      int y1i = min(y0 + 1, H_ - 1);
      float ly = yc - (float)y0;
      float hy = 1.0f - ly;
      ymin = min(ymin, y0); ymax = max(ymax, y1i);
      if (p == myph) {
        rowv[2 * iy] = y0;  rowv[2 * iy + 1] = y1i;
        wy[2 * iy] = hy * v; wy[2 * iy + 1] = ly * v;
      }
    }
  }
  int cc2[2]; float wxl[2], wxr[2];
#pragma unroll
  for (int p = 0; p < PW_; ++p) {
#pragma unroll
    for (int ix = 0; ix < 2; ++ix) {
      float x = rx1 + (float)p * bin_w + ((float)ix + 0.5f) * bin_w * 0.5f;
      float v = (x >= -1.0f && x <= (float)W_) ? 0.25f : 0.0f;
      float xc = fminf(fmaxf(x, 0.0f), (float)(W_ - 1));
      int x0 = (int)floorf(xc);
      float lx = xc - (float)x0;
      float hx = 1.0f - lx;
      int c; float wl, wr;
      if (x0 >= W_ - 1) { c = W_ - 2; wl = 0.0f; wr = hx * v; }
      else              { c = x0;     wl = hx * v; wr = lx * v; }
      cmin = min(cmin, c); cmax = max(cmax, c);
      if (p == mypw) { cc2[ix] = c; wxl[ix] = wl; wxr[ix] = wr; }
    }
  }

  const int xs4 = cmin & ~3;
  const int ng4 = ((cmax + 5 - xs4) >> 2) | 1;  // odd -> stride hits all banks
  const int nf4 = (ymax - ymin + 1) * ng4;      // <= 288
  const int S4  = 4 * ng4;                      // row stride in floats

  // ---- staging descriptors (linear packed layout) ----
  int goff[5];
#pragma unroll
  for (int i = 0; i < 5; ++i) {
    int idx = lane + 64 * i;
    int ii = min(idx, nf4 - 1);
    int row = ii / ng4;
    int g = ii - row * ng4;
    goff[i] = (ymin + row) * W_ + xs4 + 4 * g;
  }

  // ---- compute descriptors: 8 adjacent-pair taps ----
  int a8[8]; float wl8[8], wr8[8];
#pragma unroll
  for (int r = 0; r < 4; ++r)
#pragma unroll
    for (int s = 0; s < 2; ++s) {
      int q = r * 2 + s;
      a8[q] = (rowv[r] - ymin) * S4 + (cc2[s] - xs4);
      wl8[q] = wy[r] * wxl[s];
      wr8[q] = wy[r] * wxr[s];
    }

  const int cbase = chunk * CPB + wid * CPW;   // 8 consecutive channels per wave
  const float* fptr = feat + (size_t)base + (size_t)cbase * HW_;
  float* optr = out + (size_t)n * (C_ * NBIN) + cbase * NBIN + lane;
  const float* fend = feat + (MAXE - 4);
  char* b0 = smem + wid * WAVE_LDS;

  const int K = (nf4 + 63) >> 6;             // 1..5, wave-uniform
  switch (K) {
    case 1: BODY3(1, 2, 1); break;           // depth 3: waits 2,1,0
    case 2: BODY3(2, 4, 2); break;           // depth 3: waits 4,2,0
    case 3: BODY2(3); break;                 // depth 2: waits 3,0
    case 4: BODY2(4); break;
    default: BODY2(5); break;
  }
}

extern "C" void kernel_launch(void* const* d_in, const int* in_sizes, int n_in,
                              void* d_out, int out_size, void* d_ws, size_t ws_size,
                              hipStream_t stream) {
  const float* feat = (const float*)d_in[0];
  const float* rois = (const float*)d_in[1];
  float* out = (float*)d_out;
  int N = in_sizes[1] / 5;  // rois is (N,5)
  roialign_kernel<<<dim3(N * (C_ / CPB)), dim3(128), 0, stream>>>(feat, rois,
                                                                  out, N);
}